// Round 1
// baseline (903.787 us; speedup 1.0000x reference)
//
#include <hip/hip_runtime.h>
#include <math.h>

#define NN 50000
#define EE 400000
#define FIN 128
#define HH 256
#define BN_EPS 1e-5f

// ---------------- graph prep ----------------

__global__ void k_count(const int* __restrict__ dst, int* __restrict__ cnt) {
    int e = blockIdx.x * 256 + threadIdx.x;
    if (e < EE) atomicAdd(&cnt[dst[e]], 1);
}

__global__ void k_dinv(const int* __restrict__ cnt, float* __restrict__ dinv) {
    int n = blockIdx.x * 256 + threadIdx.x;
    if (n < NN) dinv[n] = rsqrtf((float)(cnt[n] + 1));  // +1 self loop
}

__global__ __launch_bounds__(1024) void k_scan(const int* __restrict__ cnt,
                                               int* __restrict__ row_start,
                                               int* __restrict__ cursor) {
    __shared__ int sums[1024];
    int tid = threadIdx.x;
    const int per = (NN + 1023) / 1024;
    int beg = tid * per;
    int end = min(beg + per, NN);
    int s = 0;
    for (int i = beg; i < end; ++i) s += cnt[i];
    sums[tid] = s;
    __syncthreads();
    for (int off = 1; off < 1024; off <<= 1) {
        int v = (tid >= off) ? sums[tid - off] : 0;
        __syncthreads();
        if (tid >= off) sums[tid] += v;
        __syncthreads();
    }
    int prefix = (tid == 0) ? 0 : sums[tid - 1];
    for (int i = beg; i < end; ++i) {
        row_start[i] = prefix;
        cursor[i] = prefix;
        prefix += cnt[i];
    }
    if (tid == 0) row_start[NN] = sums[1023];
}

__global__ void k_fill(const int* __restrict__ src, const int* __restrict__ dst,
                       int* __restrict__ cursor, int* __restrict__ csr_src) {
    int e = blockIdx.x * 256 + threadIdx.x;
    if (e < EE) {
        int pos = atomicAdd(&cursor[dst[e]], 1);
        csr_src[pos] = src[e];
    }
}

// Wcat[k][c] (256x512): c<256 -> Wm1[k][c]; else Wm1[256+k][c-256]
__global__ void k_wcat(const float* __restrict__ Wm1, float* __restrict__ Wcat) {
    int i = blockIdx.x * 256 + threadIdx.x;
    if (i < 256 * 512) {
        int k = i >> 9, c = i & 511;
        Wcat[i] = (c < 256) ? Wm1[k * 256 + c] : Wm1[(256 + k) * 256 + (c - 256)];
    }
}

// ---------------- fp32 tiled GEMM: Out[M,NC] = (rowscale ? diag(rowscale) : I) * X[M,K] @ W[K,NC] ----------------
// BM=BN=64, BK=32, 256 threads, 4x4 microtile.

__global__ __launch_bounds__(256) void gemm_rs(const float* __restrict__ X,
                                               const float* __restrict__ W,
                                               const float* __restrict__ rowscale,
                                               float* __restrict__ Out,
                                               int M, int K, int NC) {
    __shared__ float As[32][68];   // transposed: As[k][m]
    __shared__ float Bs[32][68];   // Bs[k][n]
    int m0 = blockIdx.y * 64;
    int n0 = blockIdx.x * 64;
    int tid = threadIdx.x;
    int tr0 = (tid >> 4) * 4;
    int tc0 = (tid & 15) * 4;
    float acc[4][4] = {};
    for (int k0 = 0; k0 < K; k0 += 32) {
        // load A tile 64x32 (2 passes of 256 float4)
#pragma unroll
        for (int p = 0; p < 2; ++p) {
            int r = (tid >> 3) + p * 32;
            int c4 = (tid & 7) * 4;
            int gm = m0 + r;
            float4 v = make_float4(0.f, 0.f, 0.f, 0.f);
            if (gm < M) v = *reinterpret_cast<const float4*>(X + (size_t)gm * K + k0 + c4);
            As[c4 + 0][r] = v.x;
            As[c4 + 1][r] = v.y;
            As[c4 + 2][r] = v.z;
            As[c4 + 3][r] = v.w;
        }
        // load B tile 32x64 (2 passes of 256 float4)
#pragma unroll
        for (int p = 0; p < 2; ++p) {
            int kk = (tid >> 4) + p * 16;
            int c4 = (tid & 15) * 4;
            float4 v = *reinterpret_cast<const float4*>(W + (size_t)(k0 + kk) * NC + n0 + c4);
            *reinterpret_cast<float4*>(&Bs[kk][c4]) = v;
        }
        __syncthreads();
#pragma unroll
        for (int k = 0; k < 32; ++k) {
            float4 a = *reinterpret_cast<const float4*>(&As[k][tr0]);
            float4 b = *reinterpret_cast<const float4*>(&Bs[k][tc0]);
            float av[4] = {a.x, a.y, a.z, a.w};
            float bv[4] = {b.x, b.y, b.z, b.w};
#pragma unroll
            for (int i = 0; i < 4; ++i)
#pragma unroll
                for (int j = 0; j < 4; ++j) acc[i][j] += av[i] * bv[j];
        }
        __syncthreads();
    }
#pragma unroll
    for (int i = 0; i < 4; ++i) {
        int gm = m0 + tr0 + i;
        if (gm >= M) continue;
        float sc = rowscale ? rowscale[gm] : 1.0f;
        float4 o = make_float4(acc[i][0] * sc, acc[i][1] * sc, acc[i][2] * sc, acc[i][3] * sc);
        *reinterpret_cast<float4*>(Out + (size_t)gm * NC + n0 + tc0) = o;
    }
}

// ---------------- CSR aggregation: Out[n] = dinv[n]*(Y[n] + sum_{j in row n} Y[csr_src[j]]) + bias ----------------

__global__ __launch_bounds__(256) void k_aggregate(const float* __restrict__ Y,
                                                   const int* __restrict__ csr_src,
                                                   const int* __restrict__ row_start,
                                                   const float* __restrict__ dinv,
                                                   const float* __restrict__ bias,
                                                   float* __restrict__ Out, int do_relu) {
    int n = blockIdx.x;
    int c = threadIdx.x;
    float v = Y[(size_t)n * HH + c];  // self loop
    int s0 = row_start[n], s1 = row_start[n + 1];
    for (int j = s0; j < s1; ++j) {
        int s = csr_src[j];
        v += Y[(size_t)s * HH + c];
    }
    float o = dinv[n] * v + bias[c];
    if (do_relu) o = fmaxf(o, 0.0f);
    Out[(size_t)n * HH + c] = o;
}

// ---------------- BatchNorm ----------------

__global__ __launch_bounds__(256) void k_bn_stats(const float* __restrict__ Hm,
                                                  float* __restrict__ ssum,
                                                  float* __restrict__ ssq) {
    int c = threadIdx.x;
    int r0 = blockIdx.x * 64;
    int r1 = min(r0 + 64, NN);
    float s = 0.f, q = 0.f;
    for (int r = r0; r < r1; ++r) {
        float v = Hm[(size_t)r * HH + c];
        s += v;
        q += v * v;
    }
    atomicAdd(&ssum[c], s);
    atomicAdd(&ssq[c], q);
}

__global__ void k_bn_final(const float* __restrict__ ssum, const float* __restrict__ ssq,
                           const float* __restrict__ gamma, const float* __restrict__ beta,
                           float* __restrict__ scale, float* __restrict__ shift) {
    int c = threadIdx.x;
    float mu = ssum[c] / (float)NN;
    float var = ssq[c] / (float)NN - mu * mu;
    float rstd = rsqrtf(var + BN_EPS);
    float sc = rstd * gamma[c];
    scale[c] = sc;
    shift[c] = beta[c] - mu * sc;
}

__global__ void k_bn_apply(float* __restrict__ Hm, const float* __restrict__ scale,
                           const float* __restrict__ shift) {
    int i4 = blockIdx.x * 256 + threadIdx.x;
    if (i4 < NN * HH / 4) {
        int c4 = i4 & 63;
        float4 v = reinterpret_cast<float4*>(Hm)[i4];
        float4 sc = reinterpret_cast<const float4*>(scale)[c4];
        float4 sh = reinterpret_cast<const float4*>(shift)[c4];
        v.x = fmaxf(v.x * sc.x + sh.x, 0.f);
        v.y = fmaxf(v.y * sc.y + sh.y, 0.f);
        v.z = fmaxf(v.z * sc.z + sh.z, 0.f);
        v.w = fmaxf(v.w * sc.w + sh.w, 0.f);
        reinterpret_cast<float4*>(Hm)[i4] = v;
    }
}

// ---------------- edge head: sigmoid(relu(A[src]+B[dst]+bm1) . Wm2 + bm2) ----------------
// one wave (64 lanes) per edge; AB is [N,512] with A = cols 0..255, B = cols 256..511

__global__ __launch_bounds__(256) void k_edge(const float* __restrict__ AB,
                                              const int* __restrict__ src,
                                              const int* __restrict__ dst,
                                              const float* __restrict__ bm1,
                                              const float* __restrict__ Wm2,
                                              const float* __restrict__ bm2,
                                              float* __restrict__ out) {
    int wave = threadIdx.x >> 6;
    int lane = threadIdx.x & 63;
    int e = blockIdx.x * 4 + wave;
    if (e >= EE) return;
    int s = src[e], d = dst[e];
    float4 a = reinterpret_cast<const float4*>(AB + (size_t)s * 512)[lane];
    float4 b = reinterpret_cast<const float4*>(AB + (size_t)d * 512 + 256)[lane];
    float4 bb = reinterpret_cast<const float4*>(bm1)[lane];
    float4 w = reinterpret_cast<const float4*>(Wm2)[lane];
    float t = fmaxf(a.x + b.x + bb.x, 0.f) * w.x
            + fmaxf(a.y + b.y + bb.y, 0.f) * w.y
            + fmaxf(a.z + b.z + bb.z, 0.f) * w.z
            + fmaxf(a.w + b.w + bb.w, 0.f) * w.w;
#pragma unroll
    for (int off = 32; off; off >>= 1) t += __shfl_xor(t, off);
    if (lane == 0) {
        float z = t + bm2[0];
        out[e] = 1.0f / (1.0f + expf(-z));
    }
}

// ---------------- launch ----------------

extern "C" void kernel_launch(void* const* d_in, const int* in_sizes, int n_in,
                              void* d_out, int out_size, void* d_ws, size_t ws_size,
                              hipStream_t stream) {
    const float* x     = (const float*)d_in[0];
    const int*   ei    = (const int*)d_in[1];
    const float* W1    = (const float*)d_in[2];
    const float* b1    = (const float*)d_in[3];
    const float* gamma = (const float*)d_in[4];
    const float* beta  = (const float*)d_in[5];
    const float* W2    = (const float*)d_in[6];
    const float* b2    = (const float*)d_in[7];
    const float* Wm1   = (const float*)d_in[8];
    const float* bm1   = (const float*)d_in[9];
    const float* Wm2   = (const float*)d_in[10];
    const float* bm2   = (const float*)d_in[11];
    float* out = (float*)d_out;
    const int* src = ei;
    const int* dst = ei + EE;

    char* ws = (char*)d_ws;
    size_t off = 0;
    auto take = [&](size_t b) -> char* {
        char* p = ws + off;
        off += (b + 255) & ~(size_t)255;
        return p;
    };
    int*   deg_cnt   = (int*)take((size_t)NN * 4);
    float* dinv      = (float*)take((size_t)NN * 4);
    int*   row_start = (int*)take((size_t)(NN + 1) * 4);
    int*   cursor    = (int*)take((size_t)NN * 4);
    int*   csr_src   = (int*)take((size_t)EE * 4);
    float* ssum      = (float*)take(256 * 4);   // ssq adjacent (1024B aligned)
    float* ssq       = (float*)take(256 * 4);
    float* scale     = (float*)take(256 * 4);
    float* shift     = (float*)take(256 * 4);
    float* Wcat      = (float*)take((size_t)256 * 512 * 4);
    const size_t NB = (size_t)NN * HH * 4;  // 51,200,000 (mult of 256 -> B1,B2 contiguous)
    float* B1 = (float*)take(NB);
    float* B2 = (float*)take(NB);
    float* B3 = (float*)take(NB);
    (void)ssq;

    hipMemsetAsync(deg_cnt, 0, (size_t)NN * 4, stream);
    hipMemsetAsync(ssum, 0, 2048, stream);  // ssum + ssq

    k_count<<<(EE + 255) / 256, 256, 0, stream>>>(dst, deg_cnt);
    k_dinv<<<(NN + 255) / 256, 256, 0, stream>>>(deg_cnt, dinv);
    k_scan<<<1, 1024, 0, stream>>>(deg_cnt, row_start, cursor);
    k_fill<<<(EE + 255) / 256, 256, 0, stream>>>(src, dst, cursor, csr_src);
    k_wcat<<<(256 * 512 + 255) / 256, 256, 0, stream>>>(Wm1, Wcat);

    dim3 g1(256 / 64, (NN + 63) / 64);
    // y1 = dinv * (x @ W1)
    gemm_rs<<<g1, 256, 0, stream>>>(x, W1, dinv, B1, NN, FIN, 256);
    // h1pre = dinv*(y1 + gathered) + b1
    k_aggregate<<<NN, 256, 0, stream>>>(B1, csr_src, row_start, dinv, b1, B2, 0);
    // batchnorm + relu (in place on B2)
    k_bn_stats<<<(NN + 63) / 64, 256, 0, stream>>>(B2, ssum, ssq);
    k_bn_final<<<1, 256, 0, stream>>>(ssum, ssq, gamma, beta, scale, shift);
    k_bn_apply<<<(NN * HH / 4 + 255) / 256, 256, 0, stream>>>(B2, scale, shift);
    // y2 = dinv * (h1 @ W2)
    gemm_rs<<<g1, 256, 0, stream>>>(B2, W2, dinv, B1, NN, HH, 256);
    // h2 = relu(dinv*(y2 + gathered) + b2)
    k_aggregate<<<NN, 256, 0, stream>>>(B1, csr_src, row_start, dinv, b2, B3, 1);
    // AB[n, 0:512] = h2 @ Wcat  (A | B), written across B1+B2 (contiguous 102.4MB)
    dim3 g3(512 / 64, (NN + 63) / 64);
    gemm_rs<<<g3, 256, 0, stream>>>(B3, Wcat, nullptr, B1, NN, HH, 512);
    // edge head
    k_edge<<<(EE + 3) / 4, 256, 0, stream>>>(B1, src, dst, bm1, Wm2, bm2, out);
}

// Round 4
// 841.401 us; speedup vs baseline: 1.0741x; 1.0741x over previous
//
#include <hip/hip_runtime.h>
#include <math.h>

#define NN 50000
#define EE 400000
#define FIN 128
#define HH 256
#define BN_EPS 1e-5f

typedef __attribute__((ext_vector_type(8))) short short8v;
typedef __attribute__((ext_vector_type(4))) short short4v;
typedef __attribute__((ext_vector_type(4))) float f32x4;

__device__ inline short f2bf(float x) {
    union { float f; unsigned u; } c; c.f = x;
    unsigned r = c.u + 0x7FFF + ((c.u >> 16) & 1);   // RNE
    return (short)(r >> 16);
}
__device__ inline float bf2f(short b) {
    union { unsigned u; float f; } c; c.u = ((unsigned)(unsigned short)b) << 16;
    return c.f;
}

// ---------------- graph prep ----------------

__global__ void k_count(const int* __restrict__ dst, int* __restrict__ cnt) {
    int e = blockIdx.x * 256 + threadIdx.x;
    if (e < EE) atomicAdd(&cnt[dst[e]], 1);
}

__global__ void k_dinv(const int* __restrict__ cnt, float* __restrict__ dinv) {
    int n = blockIdx.x * 256 + threadIdx.x;
    if (n < NN) dinv[n] = rsqrtf((float)(cnt[n] + 1));
}

__global__ __launch_bounds__(1024) void k_scan(const int* __restrict__ cnt,
                                               int* __restrict__ row_start,
                                               int* __restrict__ cursor) {
    __shared__ int sums[1024];
    int tid = threadIdx.x;
    const int per = (NN + 1023) / 1024;
    int beg = tid * per;
    int end = min(beg + per, NN);
    int s = 0;
    for (int i = beg; i < end; ++i) s += cnt[i];
    sums[tid] = s;
    __syncthreads();
    for (int off = 1; off < 1024; off <<= 1) {
        int v = (tid >= off) ? sums[tid - off] : 0;
        __syncthreads();
        if (tid >= off) sums[tid] += v;
        __syncthreads();
    }
    int prefix = (tid == 0) ? 0 : sums[tid - 1];
    for (int i = beg; i < end; ++i) {
        row_start[i] = prefix;
        cursor[i] = prefix;
        prefix += cnt[i];
    }
    if (tid == 0) row_start[NN] = sums[1023];
}

__global__ void k_fill(const int* __restrict__ src, const int* __restrict__ dst,
                       int* __restrict__ cursor, int* __restrict__ csr_src) {
    int e = blockIdx.x * 256 + threadIdx.x;
    if (e < EE) {
        int pos = atomicAdd(&cursor[dst[e]], 1);
        csr_src[pos] = src[e];
    }
}

// split fp32 X [M][K] row-major -> hi/lo bf16 row-major (4 elems/thread)
__global__ void k_splitA(const float* __restrict__ X, short* __restrict__ hi,
                         short* __restrict__ lo, int total4) {
    int i = blockIdx.x * 256 + threadIdx.x;
    if (i >= total4) return;
    float4 v = reinterpret_cast<const float4*>(X)[i];
    float a[4] = {v.x, v.y, v.z, v.w};
    short4v h, lw;
#pragma unroll
    for (int j = 0; j < 4; ++j) {
        short hh = f2bf(a[j]);
        h[j] = hh;
        lw[j] = f2bf(a[j] - bf2f(hh));
    }
    *(short4v*)(hi + (size_t)i * 4) = h;
    *(short4v*)(lo + (size_t)i * 4) = lw;
}

// split fp32 W [K][NC] row-major -> hi/lo bf16 in k-group-major layout [K/8][NC][8]
__global__ void k_wsplit(const float* __restrict__ src, short* __restrict__ hi,
                         short* __restrict__ lo, int K, int NC) {
    int i = blockIdx.x * 256 + threadIdx.x;
    if (i >= K * NC) return;
    int k = i / NC, n = i - k * NC;
    float v = src[i];
    short h = f2bf(v);
    short lw = f2bf(v - bf2f(h));
    size_t d = ((size_t)(k >> 3) * NC + n) * 8 + (k & 7);
    hi[d] = h;
    lo[d] = lw;
}

// Wcat[k][c] (256x512) = [Wm1_top | Wm1_bot], split to hi/lo k-group-major directly
__global__ void k_wsplit_cat(const float* __restrict__ Wm1, short* __restrict__ hi,
                             short* __restrict__ lo) {
    int i = blockIdx.x * 256 + threadIdx.x;
    if (i >= 256 * 512) return;
    int k = i >> 9, c = i & 511;
    float v = (c < 256) ? Wm1[k * 256 + c] : Wm1[(256 + k) * 256 + (c - 256)];
    short h = f2bf(v);
    short lw = f2bf(v - bf2f(h));
    size_t d = ((size_t)(k >> 3) * 512 + c) * 8 + (k & 7);
    hi[d] = h;
    lo[d] = lw;
}

// ---------------- bf16-split MFMA GEMM ----------------
// Out[:, 0:split) / OutB[:, 0:NC-split) = diag(rowscale) * A[M,K] @ B[K,NC]
// A as hi/lo bf16 row-major; B as hi/lo bf16 in [K/8][NC][8] layout.
// 64x64 block, 4 waves (32x32 each); A panel staged to LDS once; B frags in regs.

template<int K>
__global__ __launch_bounds__(256, 2) void gemm_mfma(
    const short* __restrict__ Ahi, const short* __restrict__ Alo,
    const short* __restrict__ Bthi, const short* __restrict__ Btlo,
    const float* __restrict__ rowscale, float* __restrict__ Out,
    float* __restrict__ OutB, int M, int NC, int split)
{
    constexpr int NKT = K / 32;
    constexpr int NSLAB = K / 8;
    __shared__ short lds[2 * NSLAB * 512];
    const int tid = threadIdx.x;
    const int w = tid >> 6, l = tid & 63;
    const int wr = w >> 1, wc = w & 1;
    const int m0 = blockIdx.y * 64;
    const int n0 = blockIdx.x * 64 + wc * 32;
    const int lhi = l >> 4, llo = l & 15;

    for (int s = w; s < 2 * NSLAB; s += 4) {
        int kg = (s < NSLAB) ? s : (s - NSLAB);
        const short* srcp = (s < NSLAB) ? Ahi : Alo;
        int row = m0 + l;
        if (row > M - 1) row = M - 1;
        short8v v = *(const short8v*)(srcp + (size_t)row * K + kg * 8);
        *(short8v*)(&lds[s * 512 + l * 8]) = v;
    }

    short8v Bh[NKT][2], Bl[NKT][2];
#pragma unroll
    for (int kt = 0; kt < NKT; ++kt)
#pragma unroll
        for (int nt = 0; nt < 2; ++nt) {
            size_t idx = ((size_t)(kt * 4 + lhi) * NC + (n0 + nt * 16 + llo)) * 8;
            Bh[kt][nt] = *(const short8v*)(Bthi + idx);
            Bl[kt][nt] = *(const short8v*)(Btlo + idx);
        }

    __syncthreads();

    f32x4 acc[2][2] = {};
#pragma unroll
    for (int kt = 0; kt < NKT; ++kt) {
        short8v ah[2], al[2];
#pragma unroll
        for (int mt = 0; mt < 2; ++mt) {
            int off = (kt * 4 + lhi) * 512 + (wr * 32 + mt * 16 + llo) * 8;
            ah[mt] = *(const short8v*)(&lds[off]);
            al[mt] = *(const short8v*)(&lds[off + NSLAB * 512]);
        }
#pragma unroll
        for (int mt = 0; mt < 2; ++mt)
#pragma unroll
            for (int nt = 0; nt < 2; ++nt) {
                acc[mt][nt] = __builtin_amdgcn_mfma_f32_16x16x32_bf16(ah[mt], Bh[kt][nt], acc[mt][nt], 0, 0, 0);
                acc[mt][nt] = __builtin_amdgcn_mfma_f32_16x16x32_bf16(ah[mt], Bl[kt][nt], acc[mt][nt], 0, 0, 0);
                acc[mt][nt] = __builtin_amdgcn_mfma_f32_16x16x32_bf16(al[mt], Bh[kt][nt], acc[mt][nt], 0, 0, 0);
            }
    }

    // C/D: col = lane&15, row = (lane>>4)*4 + r
#pragma unroll
    for (int mt = 0; mt < 2; ++mt)
#pragma unroll
        for (int r = 0; r < 4; ++r) {
            int gm = m0 + wr * 32 + mt * 16 + lhi * 4 + r;
            if (gm >= M) continue;
            float sc = rowscale ? rowscale[gm] : 1.0f;
#pragma unroll
            for (int nt = 0; nt < 2; ++nt) {
                int colbase = n0 + nt * 16;
                float v = acc[mt][nt][r] * sc;
                if (colbase < split)
                    Out[(size_t)gm * split + colbase + llo] = v;
                else
                    OutB[(size_t)gm * (NC - split) + (colbase - split) + llo] = v;
            }
        }
}

// ---------------- CSR aggregation ----------------

__global__ __launch_bounds__(256) void k_aggregate(const float* __restrict__ Y,
                                                   const int* __restrict__ csr_src,
                                                   const int* __restrict__ row_start,
                                                   const float* __restrict__ dinv,
                                                   const float* __restrict__ bias,
                                                   float* __restrict__ Out) {
    int n = blockIdx.x;
    int c = threadIdx.x;
    float v = Y[(size_t)n * HH + c];
    int s0 = row_start[n], s1 = row_start[n + 1];
    for (int j = s0; j < s1; ++j) v += Y[(size_t)csr_src[j] * HH + c];
    Out[(size_t)n * HH + c] = dinv[n] * v + bias[c];
}

// aggregation + bias + relu -> bf16 hi/lo
__global__ __launch_bounds__(256) void k_aggregate_bf(const float* __restrict__ Y,
                                                      const int* __restrict__ csr_src,
                                                      const int* __restrict__ row_start,
                                                      const float* __restrict__ dinv,
                                                      const float* __restrict__ bias,
                                                      short* __restrict__ Hhi,
                                                      short* __restrict__ Hlo) {
    int n = blockIdx.x;
    int c = threadIdx.x;
    float v = Y[(size_t)n * HH + c];
    int s0 = row_start[n], s1 = row_start[n + 1];
    for (int j = s0; j < s1; ++j) v += Y[(size_t)csr_src[j] * HH + c];
    float o = fmaxf(dinv[n] * v + bias[c], 0.0f);
    short h = f2bf(o);
    Hhi[(size_t)n * HH + c] = h;
    Hlo[(size_t)n * HH + c] = f2bf(o - bf2f(h));
}

// ---------------- BatchNorm ----------------

__global__ __launch_bounds__(256) void k_bn_stats(const float* __restrict__ Hm,
                                                  float* __restrict__ ssum,
                                                  float* __restrict__ ssq) {
    int c = threadIdx.x;
    int r0 = blockIdx.x * 64;
    int r1 = min(r0 + 64, NN);
    float s = 0.f, q = 0.f;
    for (int r = r0; r < r1; ++r) {
        float v = Hm[(size_t)r * HH + c];
        s += v;
        q += v * v;
    }
    atomicAdd(&ssum[c], s);
    atomicAdd(&ssq[c], q);
}

__global__ void k_bn_final(const float* __restrict__ ssum, const float* __restrict__ ssq,
                           const float* __restrict__ gamma, const float* __restrict__ beta,
                           float* __restrict__ scale, float* __restrict__ shift) {
    int c = threadIdx.x;
    float mu = ssum[c] / (float)NN;
    float var = ssq[c] / (float)NN - mu * mu;
    float rstd = rsqrtf(var + BN_EPS);
    float sc = rstd * gamma[c];
    scale[c] = sc;
    shift[c] = beta[c] - mu * sc;
}

// BN affine + relu -> bf16 hi/lo
__global__ void k_bn_apply_bf(const float* __restrict__ Hm, const float* __restrict__ scale,
                              const float* __restrict__ shift, short* __restrict__ hi,
                              short* __restrict__ lo) {
    int i4 = blockIdx.x * 256 + threadIdx.x;
    if (i4 >= NN * HH / 4) return;
    int c4 = i4 & 63;
    float4 v = reinterpret_cast<const float4*>(Hm)[i4];
    float4 sc = reinterpret_cast<const float4*>(scale)[c4];
    float4 sh = reinterpret_cast<const float4*>(shift)[c4];
    float o[4] = {fmaxf(v.x * sc.x + sh.x, 0.f), fmaxf(v.y * sc.y + sh.y, 0.f),
                  fmaxf(v.z * sc.z + sh.z, 0.f), fmaxf(v.w * sc.w + sh.w, 0.f)};
    short4v h, lw;
#pragma unroll
    for (int j = 0; j < 4; ++j) {
        short hh = f2bf(o[j]);
        h[j] = hh;
        lw[j] = f2bf(o[j] - bf2f(hh));
    }
    *(short4v*)(hi + (size_t)i4 * 4) = h;
    *(short4v*)(lo + (size_t)i4 * 4) = lw;
}

// ---------------- edge head: sigmoid(relu(Aarr[src]+Barr[dst]+bm1) . Wm2 + bm2) ----------------

__global__ __launch_bounds__(256) void k_edge(const float* __restrict__ Aarr,
                                              const float* __restrict__ Barr,
                                              const int* __restrict__ src,
                                              const int* __restrict__ dst,
                                              const float* __restrict__ bm1,
                                              const float* __restrict__ Wm2,
                                              const float* __restrict__ bm2,
                                              float* __restrict__ out) {
    int wave = threadIdx.x >> 6;
    int lane = threadIdx.x & 63;
    int e = blockIdx.x * 4 + wave;
    if (e >= EE) return;
    int s = src[e], d = dst[e];
    float4 a = reinterpret_cast<const float4*>(Aarr + (size_t)s * 256)[lane];
    float4 b = reinterpret_cast<const float4*>(Barr + (size_t)d * 256)[lane];
    float4 bb = reinterpret_cast<const float4*>(bm1)[lane];
    float4 w = reinterpret_cast<const float4*>(Wm2)[lane];
    float t = fmaxf(a.x + b.x + bb.x, 0.f) * w.x
            + fmaxf(a.y + b.y + bb.y, 0.f) * w.y
            + fmaxf(a.z + b.z + bb.z, 0.f) * w.z
            + fmaxf(a.w + b.w + bb.w, 0.f) * w.w;
#pragma unroll
    for (int off = 32; off; off >>= 1) t += __shfl_xor(t, off);
    if (lane == 0) {
        float z = t + bm2[0];
        out[e] = 1.0f / (1.0f + expf(-z));
    }
}

// ---------------- launch ----------------

extern "C" void kernel_launch(void* const* d_in, const int* in_sizes, int n_in,
                              void* d_out, int out_size, void* d_ws, size_t ws_size,
                              hipStream_t stream) {
    const float* x     = (const float*)d_in[0];
    const int*   ei    = (const int*)d_in[1];
    const float* W1    = (const float*)d_in[2];
    const float* b1    = (const float*)d_in[3];
    const float* gamma = (const float*)d_in[4];
    const float* beta  = (const float*)d_in[5];
    const float* W2    = (const float*)d_in[6];
    const float* b2    = (const float*)d_in[7];
    const float* Wm1   = (const float*)d_in[8];
    const float* bm1   = (const float*)d_in[9];
    const float* Wm2   = (const float*)d_in[10];
    const float* bm2   = (const float*)d_in[11];
    float* out = (float*)d_out;
    const int* src = ei;
    const int* dst = ei + EE;

    char* ws = (char*)d_ws;
    size_t off = 0;
    auto take = [&](size_t b) -> char* {
        char* p = ws + off;
        off += (b + 255) & ~(size_t)255;
        return p;
    };
    // small tables first (~3.32 MB)
    int*   deg_cnt   = (int*)take((size_t)NN * 4);
    float* dinv      = (float*)take((size_t)NN * 4);
    int*   row_start = (int*)take((size_t)(NN + 1) * 4);
    int*   cursor    = (int*)take((size_t)NN * 4);
    int*   csr_src   = (int*)take((size_t)EE * 4);
    float* ssum      = (float*)take(1024);
    float* ssq       = (float*)take(1024);
    float* scale     = (float*)take(1024);
    float* shift     = (float*)take(1024);
    short* W1thi     = (short*)take((size_t)128 * 256 * 2);
    short* W1tlo     = (short*)take((size_t)128 * 256 * 2);
    short* W2thi     = (short*)take((size_t)256 * 256 * 2);
    short* W2tlo     = (short*)take((size_t)256 * 256 * 2);
    short* Wcthi     = (short*)take((size_t)256 * 512 * 2);
    short* Wctlo     = (short*)take((size_t)256 * 512 * 2);
    // three 51.2 MB slots, liveness-aliased; peak total ~156.9 MB (round-1's
    // 157.6 MB layout is known to fit ws_size; round-2's 208.8 MB crashed).
    const size_t SLOT = (size_t)NN * HH * 4;  // 51,200,000
    char* slotA = take(SLOT);
    char* slotB = take(SLOT);
    char* slotC = take(SLOT);

    short* Xhi  = (short*)slotC;                    // [N,128] bf16 x2 = 25.6MB
    short* Xlo  = (short*)(slotC + SLOT / 2);
    float* Y1   = (float*)slotA;                    // gemm1 out
    float* P1   = (float*)slotB;                    // agg1 out (pre-BN)
    short* H1hi = (short*)slotA;                    // bn out (Y1 dead)
    short* H1lo = (short*)(slotA + SLOT / 2);
    float* Y2   = (float*)slotC;                    // gemm2 out (X dead)
    short* H2hi = (short*)slotB;                    // agg2 out (P1 dead)
    short* H2lo = (short*)(slotB + SLOT / 2);
    float* Aarr = (float*)slotA;                    // gemm3 out A-half (H1 dead)
    float* Barr = (float*)slotC;                    // gemm3 out B-half (Y2 dead)
    (void)ssq; (void)ws_size;

    hipMemsetAsync(deg_cnt, 0, (size_t)NN * 4, stream);
    hipMemsetAsync(ssum, 0, 2048, stream);  // ssum + ssq adjacent

    k_count<<<(EE + 255) / 256, 256, 0, stream>>>(dst, deg_cnt);
    k_dinv<<<(NN + 255) / 256, 256, 0, stream>>>(deg_cnt, dinv);
    k_scan<<<1, 1024, 0, stream>>>(deg_cnt, row_start, cursor);
    k_fill<<<(EE + 255) / 256, 256, 0, stream>>>(src, dst, cursor, csr_src);
    k_splitA<<<(NN * FIN / 4 + 255) / 256, 256, 0, stream>>>(x, Xhi, Xlo, NN * FIN / 4);
    k_wsplit<<<(128 * 256 + 255) / 256, 256, 0, stream>>>(W1, W1thi, W1tlo, 128, 256);
    k_wsplit<<<(256 * 256 + 255) / 256, 256, 0, stream>>>(W2, W2thi, W2tlo, 256, 256);
    k_wsplit_cat<<<(256 * 512 + 255) / 256, 256, 0, stream>>>(Wm1, Wcthi, Wctlo);

    const int MB = (NN + 63) / 64;  // 782
    // Y1 = dinv * (x @ W1)
    gemm_mfma<128><<<dim3(4, MB), 256, 0, stream>>>(Xhi, Xlo, W1thi, W1tlo, dinv, Y1, Y1, NN, 256, 256);
    // P1 = dinv*(Y1 + gathered) + b1
    k_aggregate<<<NN, 256, 0, stream>>>(Y1, csr_src, row_start, dinv, b1, P1);
    // batchnorm + relu -> bf16 hi/lo
    k_bn_stats<<<(NN + 63) / 64, 256, 0, stream>>>(P1, ssum, ssq);
    k_bn_final<<<1, 256, 0, stream>>>(ssum, ssq, gamma, beta, scale, shift);
    k_bn_apply_bf<<<(NN * HH / 4 + 255) / 256, 256, 0, stream>>>(P1, scale, shift, H1hi, H1lo);
    // Y2 = dinv * (h1 @ W2)
    gemm_mfma<256><<<dim3(4, MB), 256, 0, stream>>>(H1hi, H1lo, W2thi, W2tlo, dinv, Y2, Y2, NN, 256, 256);
    // H2 = relu(dinv*(Y2 + gathered) + b2) -> bf16 hi/lo
    k_aggregate_bf<<<NN, 256, 0, stream>>>(Y2, csr_src, row_start, dinv, b2, H2hi, H2lo);
    // [Aarr | Barr] = h2 @ Wcat
    gemm_mfma<256><<<dim3(8, MB), 256, 0, stream>>>(H2hi, H2lo, Wcthi, Wctlo, nullptr, Aarr, Barr, NN, 512, 256);
    // edge head
    k_edge<<<(EE + 3) / 4, 256, 0, stream>>>(Aarr, Barr, src, dst, bm1, Wm2, bm2, out);
}

// Round 5
// 656.142 us; speedup vs baseline: 1.3774x; 1.2823x over previous
//
#include <hip/hip_runtime.h>
#include <math.h>

#define NN 50000
#define EE 400000
#define FIN 128
#define HH 256
#define BN_EPS 1e-5f

typedef __attribute__((ext_vector_type(8))) short short8v;
typedef __attribute__((ext_vector_type(4))) short short4v;
typedef __attribute__((ext_vector_type(2))) short short2v;
typedef __attribute__((ext_vector_type(4))) float f32x4;

__device__ inline short f2bf(float x) {
    union { float f; unsigned u; } c; c.f = x;
    unsigned r = c.u + 0x7FFF + ((c.u >> 16) & 1);   // RNE
    return (short)(r >> 16);
}
__device__ inline float bf2f(short b) {
    union { unsigned u; float f; } c; c.u = ((unsigned)(unsigned short)b) << 16;
    return c.f;
}

// ---------------- graph prep ----------------

__global__ void k_count(const int* __restrict__ dst, int* __restrict__ cnt) {
    int e = blockIdx.x * 256 + threadIdx.x;
    if (e < EE) atomicAdd(&cnt[dst[e]], 1);
}

__global__ void k_dinv(const int* __restrict__ cnt, float* __restrict__ dinv) {
    int n = blockIdx.x * 256 + threadIdx.x;
    if (n < NN) dinv[n] = rsqrtf((float)(cnt[n] + 1));
}

__global__ __launch_bounds__(1024) void k_scan(const int* __restrict__ cnt,
                                               int* __restrict__ row_start,
                                               int* __restrict__ cursor) {
    __shared__ int sums[1024];
    int tid = threadIdx.x;
    const int per = (NN + 1023) / 1024;
    int beg = tid * per;
    int end = min(beg + per, NN);
    int s = 0;
    for (int i = beg; i < end; ++i) s += cnt[i];
    sums[tid] = s;
    __syncthreads();
    for (int off = 1; off < 1024; off <<= 1) {
        int v = (tid >= off) ? sums[tid - off] : 0;
        __syncthreads();
        if (tid >= off) sums[tid] += v;
        __syncthreads();
    }
    int prefix = (tid == 0) ? 0 : sums[tid - 1];
    for (int i = beg; i < end; ++i) {
        row_start[i] = prefix;
        cursor[i] = prefix;
        prefix += cnt[i];
    }
    if (tid == 0) row_start[NN] = sums[1023];
}

__global__ void k_fill(const int* __restrict__ src, const int* __restrict__ dst,
                       int* __restrict__ cursor, int* __restrict__ csr_src) {
    int e = blockIdx.x * 256 + threadIdx.x;
    if (e < EE) {
        int pos = atomicAdd(&cursor[dst[e]], 1);
        csr_src[pos] = src[e];
    }
}

// ---------------- operand prep ----------------

// Xs = dinv ⊙ x (row-scaled input, fp32)
__global__ void k_scaleX(const float* __restrict__ x, const float* __restrict__ dinv,
                         float* __restrict__ Xs) {
    int i4 = blockIdx.x * 256 + threadIdx.x;
    if (i4 >= NN * FIN / 4) return;
    float g = dinv[i4 >> 5];          // 32 float4 per 128-wide row
    float4 v = reinterpret_cast<const float4*>(x)[i4];
    v.x *= g; v.y *= g; v.z *= g; v.w *= g;
    reinterpret_cast<float4*>(Xs)[i4] = v;
}

// split fp32 W [K][NC] row-major -> hi/lo bf16 in k-group-major layout [K/8][NC][8]
__global__ void k_wsplit(const float* __restrict__ src, short* __restrict__ hi,
                         short* __restrict__ lo, int K, int NC) {
    int i = blockIdx.x * 256 + threadIdx.x;
    if (i >= K * NC) return;
    int k = i / NC, n = i - k * NC;
    float v = src[i];
    short h = f2bf(v);
    short lw = f2bf(v - bf2f(h));
    size_t d = ((size_t)(k >> 3) * NC + n) * 8 + (k & 7);
    hi[d] = h;
    lo[d] = lw;
}

// Wcat[k][c] (256x512) = [Wm1_top | Wm1_bot] -> hi/lo k-group-major
__global__ void k_wsplit_cat(const float* __restrict__ Wm1, short* __restrict__ hi,
                             short* __restrict__ lo) {
    int i = blockIdx.x * 256 + threadIdx.x;
    if (i >= 256 * 512) return;
    int k = i >> 9, c = i & 511;
    float v = (c < 256) ? Wm1[k * 256 + c] : Wm1[(256 + k) * 256 + (c - 256)];
    short h = f2bf(v);
    short lw = f2bf(v - bf2f(h));
    size_t d = ((size_t)(k >> 3) * 512 + c) * 8 + (k & 7);
    hi[d] = h;
    lo[d] = lw;
}

// ---------------- aggregation (gather) kernels, one wave per node ----------------

// G1 = dinv[n]*(Xs[n] + sum_{j in in(n)} Xs[j]) -> bf16 hi/lo   (128-dim)
__global__ __launch_bounds__(256) void k_aggX(const float* __restrict__ Xs,
                                              const int* __restrict__ csr_src,
                                              const int* __restrict__ row_start,
                                              const float* __restrict__ dinv,
                                              short* __restrict__ Ghi,
                                              short* __restrict__ Glo) {
    int wave = threadIdx.x >> 6, lane = threadIdx.x & 63;
    int n = blockIdx.x * 4 + wave;
    if (n >= NN) return;
    const float2* base = reinterpret_cast<const float2*>(Xs);
    float2 v = base[(size_t)n * 64 + lane];
    int s0 = row_start[n], s1 = row_start[n + 1];
    for (int j = s0; j < s1; ++j) {
        float2 u = base[(size_t)csr_src[j] * 64 + lane];
        v.x += u.x; v.y += u.y;
    }
    float g = dinv[n];
    v.x *= g; v.y *= g;
    short2v h, lw;
    short h0 = f2bf(v.x), h1 = f2bf(v.y);
    h[0] = h0; h[1] = h1;
    lw[0] = f2bf(v.x - bf2f(h0)); lw[1] = f2bf(v.y - bf2f(h1));
    *(short2v*)(Ghi + (size_t)n * FIN + lane * 2) = h;
    *(short2v*)(Glo + (size_t)n * FIN + lane * 2) = lw;
}

// G2 = dinv[n]*(T[n] + sum T[j]) -> bf16 hi/lo   (256-dim)
__global__ __launch_bounds__(256) void k_aggH(const float* __restrict__ T,
                                              const int* __restrict__ csr_src,
                                              const int* __restrict__ row_start,
                                              const float* __restrict__ dinv,
                                              short* __restrict__ Ghi,
                                              short* __restrict__ Glo) {
    int wave = threadIdx.x >> 6, lane = threadIdx.x & 63;
    int n = blockIdx.x * 4 + wave;
    if (n >= NN) return;
    const float4* base = reinterpret_cast<const float4*>(T);
    float4 v = base[(size_t)n * 64 + lane];
    int s0 = row_start[n], s1 = row_start[n + 1];
    for (int j = s0; j < s1; ++j) {
        float4 u = base[(size_t)csr_src[j] * 64 + lane];
        v.x += u.x; v.y += u.y; v.z += u.z; v.w += u.w;
    }
    float g = dinv[n];
    float o[4] = {v.x * g, v.y * g, v.z * g, v.w * g};
    short4v h, lw;
#pragma unroll
    for (int j = 0; j < 4; ++j) {
        short hh = f2bf(o[j]);
        h[j] = hh;
        lw[j] = f2bf(o[j] - bf2f(hh));
    }
    *(short4v*)(Ghi + (size_t)n * HH + lane * 4) = h;
    *(short4v*)(Glo + (size_t)n * HH + lane * 4) = lw;
}

// ---------------- bf16-split MFMA stripe GEMM ----------------
// One block per 64-row stripe; A panel (hi+lo, full K) staged to LDS once;
// loops over NC in 64-col passes. B in [K/8][NC][8] hi/lo layout (L2-resident).
// EPI: 0 = +bias, fp32 out. 1 = +bias, relu, bf16 hi/lo out. 2 = bf16 out split
// into two half-width buffers.

template<int K, int NC, int EPI>
__global__ __launch_bounds__(256, 2) void gemm_stripe(
    const short* __restrict__ Ahi, const short* __restrict__ Alo,
    const short* __restrict__ Bthi, const short* __restrict__ Btlo,
    const float* __restrict__ bias,
    float* __restrict__ OutF, short* __restrict__ OutH, short* __restrict__ OutL,
    short* __restrict__ OutA, short* __restrict__ OutB2, int M)
{
    constexpr int NKT = K / 32;
    constexpr int NSLAB = K / 8;
    constexpr int NPASS = NC / 64;
    __shared__ short lds[2 * NSLAB * 512];
    const int tid = threadIdx.x;
    const int w = tid >> 6, l = tid & 63;
    const int wr = w >> 1, wc = w & 1;
    const int m0 = blockIdx.x * 64;
    const int lhi = l >> 4, llo = l & 15;

    // stage A panel (hi then lo): slab s -> kgrp s%NSLAB, lane = row
    for (int s = w; s < 2 * NSLAB; s += 4) {
        int kg = (s < NSLAB) ? s : (s - NSLAB);
        const short* srcp = (s < NSLAB) ? Ahi : Alo;
        int row = m0 + l;
        if (row > M - 1) row = M - 1;
        short8v v = *(const short8v*)(srcp + (size_t)row * K + kg * 8);
        *(short8v*)(&lds[s * 512 + l * 8]) = v;
    }
    __syncthreads();

    for (int pass = 0; pass < NPASS; ++pass) {
        const int n0 = pass * 64 + wc * 32;
        f32x4 acc[2][2] = {};
#pragma unroll
        for (int kt = 0; kt < NKT; ++kt) {
            short8v bh[2], bl[2];
#pragma unroll
            for (int nt = 0; nt < 2; ++nt) {
                size_t idx = ((size_t)(kt * 4 + lhi) * NC + (n0 + nt * 16 + llo)) * 8;
                bh[nt] = *(const short8v*)(Bthi + idx);
                bl[nt] = *(const short8v*)(Btlo + idx);
            }
            short8v ah[2], al[2];
#pragma unroll
            for (int mt = 0; mt < 2; ++mt) {
                int off = (kt * 4 + lhi) * 512 + (wr * 32 + mt * 16 + llo) * 8;
                ah[mt] = *(const short8v*)(&lds[off]);
                al[mt] = *(const short8v*)(&lds[off + NSLAB * 512]);
            }
#pragma unroll
            for (int mt = 0; mt < 2; ++mt)
#pragma unroll
                for (int nt = 0; nt < 2; ++nt) {
                    acc[mt][nt] = __builtin_amdgcn_mfma_f32_16x16x32_bf16(ah[mt], bh[nt], acc[mt][nt], 0, 0, 0);
                    acc[mt][nt] = __builtin_amdgcn_mfma_f32_16x16x32_bf16(ah[mt], bl[nt], acc[mt][nt], 0, 0, 0);
                    acc[mt][nt] = __builtin_amdgcn_mfma_f32_16x16x32_bf16(al[mt], bh[nt], acc[mt][nt], 0, 0, 0);
                }
        }
        // epilogue: C/D layout col = lane&15, row = (lane>>4)*4 + r
#pragma unroll
        for (int mt = 0; mt < 2; ++mt)
#pragma unroll
            for (int r = 0; r < 4; ++r) {
                int gm = m0 + wr * 32 + mt * 16 + lhi * 4 + r;
                if (gm >= M) continue;
#pragma unroll
                for (int nt = 0; nt < 2; ++nt) {
                    int col = n0 + nt * 16 + llo;
                    float v = acc[mt][nt][r];
                    if constexpr (EPI == 0) {
                        OutF[(size_t)gm * NC + col] = v + bias[col];
                    } else if constexpr (EPI == 1) {
                        float o = fmaxf(v + bias[col], 0.0f);
                        short h = f2bf(o);
                        OutH[(size_t)gm * NC + col] = h;
                        OutL[(size_t)gm * NC + col] = f2bf(o - bf2f(h));
                    } else {
                        short h = f2bf(v);
                        if (col < NC / 2)
                            OutA[(size_t)gm * (NC / 2) + col] = h;
                        else
                            OutB2[(size_t)gm * (NC / 2) + col - NC / 2] = h;
                    }
                }
            }
    }
}

// ---------------- BatchNorm ----------------

__global__ __launch_bounds__(256) void k_bn_stats(const float* __restrict__ Hm,
                                                  float* __restrict__ ssum,
                                                  float* __restrict__ ssq) {
    int c = threadIdx.x;
    int r0 = blockIdx.x * 64;
    int r1 = min(r0 + 64, NN);
    float s = 0.f, q = 0.f;
    for (int r = r0; r < r1; ++r) {
        float v = Hm[(size_t)r * HH + c];
        s += v;
        q += v * v;
    }
    atomicAdd(&ssum[c], s);
    atomicAdd(&ssq[c], q);
}

__global__ void k_bn_final(const float* __restrict__ ssum, const float* __restrict__ ssq,
                           const float* __restrict__ gamma, const float* __restrict__ beta,
                           float* __restrict__ scale, float* __restrict__ shift) {
    int c = threadIdx.x;
    float mu = ssum[c] / (float)NN;
    float var = ssq[c] / (float)NN - mu * mu;
    float rstd = rsqrtf(var + BN_EPS);
    float sc = rstd * gamma[c];
    scale[c] = sc;
    shift[c] = beta[c] - mu * sc;
}

// T = dinv_row * relu(scale*P1 + shift)   (fp32, feeds layer-2 aggregation)
__global__ void k_bn_apply_T(const float* __restrict__ P1, const float* __restrict__ scale,
                             const float* __restrict__ shift, const float* __restrict__ dinv,
                             float* __restrict__ T) {
    int i4 = blockIdx.x * 256 + threadIdx.x;
    if (i4 >= NN * HH / 4) return;
    int c4 = i4 & 63;
    float g = dinv[i4 >> 6];
    float4 v = reinterpret_cast<const float4*>(P1)[i4];
    float4 sc = reinterpret_cast<const float4*>(scale)[c4];
    float4 sh = reinterpret_cast<const float4*>(shift)[c4];
    v.x = g * fmaxf(v.x * sc.x + sh.x, 0.f);
    v.y = g * fmaxf(v.y * sc.y + sh.y, 0.f);
    v.z = g * fmaxf(v.z * sc.z + sh.z, 0.f);
    v.w = g * fmaxf(v.w * sc.w + sh.w, 0.f);
    reinterpret_cast<float4*>(T)[i4] = v;
}

// ---------------- edge head: sigmoid(relu(A[src]+B[dst]+bm1) . Wm2 + bm2) ----------------
// A/B stored bf16 [N][256]; one wave per edge, 4 bf16 per lane.

__global__ __launch_bounds__(256) void k_edge(const short* __restrict__ Aarr,
                                              const short* __restrict__ Barr,
                                              const int* __restrict__ src,
                                              const int* __restrict__ dst,
                                              const float* __restrict__ bm1,
                                              const float* __restrict__ Wm2,
                                              const float* __restrict__ bm2,
                                              float* __restrict__ out) {
    int wave = threadIdx.x >> 6;
    int lane = threadIdx.x & 63;
    int e = blockIdx.x * 4 + wave;
    if (e >= EE) return;
    int s = src[e], d = dst[e];
    short4v a = *(const short4v*)(Aarr + (size_t)s * 256 + lane * 4);
    short4v b = *(const short4v*)(Barr + (size_t)d * 256 + lane * 4);
    float4 bb = reinterpret_cast<const float4*>(bm1)[lane];
    float4 w = reinterpret_cast<const float4*>(Wm2)[lane];
    float t = fmaxf(bf2f(a[0]) + bf2f(b[0]) + bb.x, 0.f) * w.x
            + fmaxf(bf2f(a[1]) + bf2f(b[1]) + bb.y, 0.f) * w.y
            + fmaxf(bf2f(a[2]) + bf2f(b[2]) + bb.z, 0.f) * w.z
            + fmaxf(bf2f(a[3]) + bf2f(b[3]) + bb.w, 0.f) * w.w;
#pragma unroll
    for (int off = 32; off; off >>= 1) t += __shfl_xor(t, off);
    if (lane == 0) {
        float z = t + bm2[0];
        out[e] = 1.0f / (1.0f + expf(-z));
    }
}

// ---------------- launch ----------------

extern "C" void kernel_launch(void* const* d_in, const int* in_sizes, int n_in,
                              void* d_out, int out_size, void* d_ws, size_t ws_size,
                              hipStream_t stream) {
    const float* x     = (const float*)d_in[0];
    const int*   ei    = (const int*)d_in[1];
    const float* W1    = (const float*)d_in[2];
    const float* b1    = (const float*)d_in[3];
    const float* gamma = (const float*)d_in[4];
    const float* beta  = (const float*)d_in[5];
    const float* W2    = (const float*)d_in[6];
    const float* b2    = (const float*)d_in[7];
    const float* Wm1   = (const float*)d_in[8];
    const float* bm1   = (const float*)d_in[9];
    const float* Wm2   = (const float*)d_in[10];
    const float* bm2   = (const float*)d_in[11];
    float* out = (float*)d_out;
    const int* src = ei;
    const int* dst = ei + EE;

    char* ws = (char*)d_ws;
    size_t off = 0;
    auto take = [&](size_t b) -> char* {
        char* p = ws + off;
        off += (b + 255) & ~(size_t)255;
        return p;
    };
    // small tables (~3.3 MB)
    int*   deg_cnt   = (int*)take((size_t)NN * 4);
    float* dinv      = (float*)take((size_t)NN * 4);
    int*   row_start = (int*)take((size_t)(NN + 1) * 4);
    int*   cursor    = (int*)take((size_t)NN * 4);
    int*   csr_src   = (int*)take((size_t)EE * 4);
    float* ssum      = (float*)take(1024);
    float* ssq       = (float*)take(1024);
    float* scale     = (float*)take(1024);
    float* shift     = (float*)take(1024);
    short* W1thi     = (short*)take((size_t)128 * 256 * 2);
    short* W1tlo     = (short*)take((size_t)128 * 256 * 2);
    short* W2thi     = (short*)take((size_t)256 * 256 * 2);
    short* W2tlo     = (short*)take((size_t)256 * 256 * 2);
    short* Wcthi     = (short*)take((size_t)256 * 512 * 2);
    short* Wctlo     = (short*)take((size_t)256 * 512 * 2);
    // three 51.2 MB slots, liveness-aliased (peak ~157 MB, known to fit)
    const size_t SLOT = (size_t)NN * HH * 4;  // 51,200,000
    char* slotA = take(SLOT);
    char* slotB = take(SLOT);
    char* slotC = take(SLOT);

    float* Xs   = (float*)slotA;                    // [N,128] fp32, 25.6 MB
    short* G1hi = (short*)slotB;                    // [N,128] bf16 12.8 MB
    short* G1lo = (short*)(slotB + 12800000);
    float* P1   = (float*)slotC;                    // [N,256] fp32
    float* T    = (float*)slotA;                    // [N,256] fp32 (Xs dead)
    short* G2hi = (short*)slotB;                    // [N,256] bf16 (G1 dead)
    short* G2lo = (short*)(slotB + 25600000);
    short* H2hi = (short*)slotC;                    // [N,256] bf16 (P1 dead)
    short* H2lo = (short*)(slotC + 25600000);
    short* Aarr = (short*)slotA;                    // [N,256] bf16 (T dead)
    short* Barr = (short*)(slotA + 25600000);
    (void)ssq; (void)ws_size;

    hipMemsetAsync(deg_cnt, 0, (size_t)NN * 4, stream);
    hipMemsetAsync(ssum, 0, 2048, stream);  // ssum + ssq adjacent

    k_count<<<(EE + 255) / 256, 256, 0, stream>>>(dst, deg_cnt);
    k_dinv<<<(NN + 255) / 256, 256, 0, stream>>>(deg_cnt, dinv);
    k_scan<<<1, 1024, 0, stream>>>(deg_cnt, row_start, cursor);
    k_fill<<<(EE + 255) / 256, 256, 0, stream>>>(src, dst, cursor, csr_src);
    k_wsplit<<<(128 * 256 + 255) / 256, 256, 0, stream>>>(W1, W1thi, W1tlo, 128, 256);
    k_wsplit<<<(256 * 256 + 255) / 256, 256, 0, stream>>>(W2, W2thi, W2tlo, 256, 256);
    k_wsplit_cat<<<(256 * 512 + 255) / 256, 256, 0, stream>>>(Wm1, Wcthi, Wctlo);

    const int MB = (NN + 63) / 64;  // 782
    // layer 1 (aggregate-first): Xs = dinv.x ; G1 = dinv*(Xs + gather) ; P1 = G1@W1 + b1
    k_scaleX<<<NN * FIN / 4 / 256, 256, 0, stream>>>(x, dinv, Xs);
    k_aggX<<<(NN + 3) / 4, 256, 0, stream>>>(Xs, csr_src, row_start, dinv, G1hi, G1lo);
    gemm_stripe<128, 256, 0><<<MB, 256, 0, stream>>>(G1hi, G1lo, W1thi, W1tlo, b1,
                                                     P1, nullptr, nullptr, nullptr, nullptr, NN);
    // batchnorm; T = dinv * relu(BN(P1))
    k_bn_stats<<<(NN + 63) / 64, 256, 0, stream>>>(P1, ssum, ssq);
    k_bn_final<<<1, 256, 0, stream>>>(ssum, ssq, gamma, beta, scale, shift);
    k_bn_apply_T<<<NN * HH / 4 / 256, 256, 0, stream>>>(P1, scale, shift, dinv, T);
    // layer 2: G2 = dinv*(T + gather) ; H2 = relu(G2@W2 + b2) (bf16 hi/lo, fused)
    k_aggH<<<(NN + 3) / 4, 256, 0, stream>>>(T, csr_src, row_start, dinv, G2hi, G2lo);
    gemm_stripe<256, 256, 1><<<MB, 256, 0, stream>>>(G2hi, G2lo, W2thi, W2tlo, b2,
                                                     nullptr, H2hi, H2lo, nullptr, nullptr, NN);
    // edge-head node factors: [Aarr | Barr] = H2 @ Wcat (bf16 out)
    gemm_stripe<256, 512, 2><<<MB, 256, 0, stream>>>(H2hi, H2lo, Wcthi, Wctlo, nullptr,
                                                     nullptr, nullptr, nullptr, Aarr, Barr, NN);
    // edge head
    k_edge<<<(EE + 3) / 4, 256, 0, stream>>>(Aarr, Barr, src, dst, bm1, Wm2, bm2, out);
}

// Round 7
// 546.046 us; speedup vs baseline: 1.6551x; 1.2016x over previous
//
#include <hip/hip_runtime.h>
#include <math.h>

#define NN 50000
#define EE 400000
#define FIN 128
#define HH 256
#define BN_EPS 1e-5f
#define NSB 196   // scan blocks = ceil(NN/256)

typedef __attribute__((ext_vector_type(8))) short short8v;
typedef __attribute__((ext_vector_type(4))) short short4v;
typedef __attribute__((ext_vector_type(2))) short short2v;
typedef __attribute__((ext_vector_type(4))) float f32x4;

__device__ inline short f2bf(float x) {
    union { float f; unsigned u; } c; c.f = x;
    unsigned r = c.u + 0x7FFF + ((c.u >> 16) & 1);   // RNE
    return (short)(r >> 16);
}
__device__ inline float bf2f(short b) {
    union { unsigned u; float f; } c; c.u = ((unsigned)(unsigned short)b) << 16;
    return c.f;
}

// ---------------- graph prep ----------------

__global__ void k_count(const int* __restrict__ dst, int* __restrict__ cnt) {
    int e = blockIdx.x * 256 + threadIdx.x;
    if (e < EE) atomicAdd(&cnt[dst[e]], 1);
}

// phase 1: per-block sums of cnt
__global__ __launch_bounds__(256) void k_scan1(const int* __restrict__ cnt,
                                               int* __restrict__ bsum) {
    __shared__ int ws4[4];
    int i = blockIdx.x * 256 + threadIdx.x;
    int s = (i < NN) ? cnt[i] : 0;
#pragma unroll
    for (int o = 32; o; o >>= 1) s += __shfl_down(s, o);
    if ((threadIdx.x & 63) == 0) ws4[threadIdx.x >> 6] = s;
    __syncthreads();
    if (threadIdx.x == 0) bsum[blockIdx.x] = ws4[0] + ws4[1] + ws4[2] + ws4[3];
}

// phase 2: exclusive scan of NSB block sums (single 256-thread block)
__global__ __launch_bounds__(256) void k_scan2(const int* __restrict__ bsum,
                                               int* __restrict__ boff,
                                               int* __restrict__ row_start) {
    __shared__ int sh[256];
    int t = threadIdx.x;
    int v = (t < NSB) ? bsum[t] : 0;
    sh[t] = v;
    __syncthreads();
    for (int o = 1; o < 256; o <<= 1) {
        int u = (t >= o) ? sh[t - o] : 0;
        __syncthreads();
        sh[t] += u;
        __syncthreads();
    }
    if (t < NSB) boff[t] = sh[t] - v;   // exclusive
    if (t == 0) row_start[NN] = EE;
}

// phase 3: local exclusive scan + block offset -> row_start/cursor; fused dinv
__global__ __launch_bounds__(256) void k_scan3(const int* __restrict__ cnt,
                                               const int* __restrict__ boff,
                                               int* __restrict__ row_start,
                                               int* __restrict__ cursor,
                                               float* __restrict__ dinv) {
    __shared__ int sh[256];
    int t = threadIdx.x;
    int i = blockIdx.x * 256 + t;
    int v = (i < NN) ? cnt[i] : 0;
    sh[t] = v;
    __syncthreads();
    for (int o = 1; o < 256; o <<= 1) {
        int u = (t >= o) ? sh[t - o] : 0;
        __syncthreads();
        sh[t] += u;
        __syncthreads();
    }
    if (i < NN) {
        int rs = boff[blockIdx.x] + sh[t] - v;
        row_start[i] = rs;
        cursor[i] = rs;
        dinv[i] = rsqrtf((float)(v + 1));
    }
}

__global__ void k_fill(const int* __restrict__ src, const int* __restrict__ dst,
                       int* __restrict__ cursor, int* __restrict__ csr_src) {
    int e = blockIdx.x * 256 + threadIdx.x;
    if (e < EE) {
        int pos = atomicAdd(&cursor[dst[e]], 1);
        csr_src[pos] = src[e];
    }
}

// ---------------- operand prep ----------------

// split fp32 W [K][NC] row-major -> hi/lo bf16 in k-group-major layout [K/8][NC][8]
__global__ void k_wsplit(const float* __restrict__ src, short* __restrict__ hi,
                         short* __restrict__ lo, int K, int NC) {
    int i = blockIdx.x * 256 + threadIdx.x;
    if (i >= K * NC) return;
    int k = i / NC, n = i - k * NC;
    float v = src[i];
    short h = f2bf(v);
    short lw = f2bf(v - bf2f(h));
    size_t d = ((size_t)(k >> 3) * NC + n) * 8 + (k & 7);
    hi[d] = h;
    lo[d] = lw;
}

// Wcat[k][c] (256x512) = [Wm1_top | Wm1_bot] -> hi/lo k-group-major
__global__ void k_wsplit_cat(const float* __restrict__ Wm1, short* __restrict__ hi,
                             short* __restrict__ lo) {
    int i = blockIdx.x * 256 + threadIdx.x;
    if (i >= 256 * 512) return;
    int k = i >> 9, c = i & 511;
    float v = (c < 256) ? Wm1[k * 256 + c] : Wm1[(256 + k) * 256 + (c - 256)];
    short h = f2bf(v);
    short lw = f2bf(v - bf2f(h));
    size_t d = ((size_t)(k >> 3) * 512 + c) * 8 + (k & 7);
    hi[d] = h;
    lo[d] = lw;
}

// ---------------- aggregation (gather) kernels, one wave per node ----------------

// G1 = dinv[n]*(dinv[n]*x[n] + sum_j dinv[j]*x[j]) -> bf16 hi/lo  (128-dim, scale fused)
__global__ __launch_bounds__(256) void k_aggX(const float* __restrict__ x,
                                              const int* __restrict__ csr_src,
                                              const int* __restrict__ row_start,
                                              const float* __restrict__ dinv,
                                              short* __restrict__ Ghi,
                                              short* __restrict__ Glo) {
    int wave = threadIdx.x >> 6, lane = threadIdx.x & 63;
    int n = blockIdx.x * 4 + wave;
    if (n >= NN) return;
    const float2* base = reinterpret_cast<const float2*>(x);
    float g = dinv[n];
    float2 v = base[(size_t)n * 64 + lane];
    v.x *= g; v.y *= g;
    int s0 = row_start[n], s1 = row_start[n + 1];
    for (int j = s0; j < s1; ++j) {
        int sj = csr_src[j];
        float gj = dinv[sj];
        float2 u = base[(size_t)sj * 64 + lane];
        v.x += gj * u.x; v.y += gj * u.y;
    }
    v.x *= g; v.y *= g;
    short2v h, lw;
    short h0 = f2bf(v.x), h1 = f2bf(v.y);
    h[0] = h0; h[1] = h1;
    lw[0] = f2bf(v.x - bf2f(h0)); lw[1] = f2bf(v.y - bf2f(h1));
    *(short2v*)(Ghi + (size_t)n * FIN + lane * 2) = h;
    *(short2v*)(Glo + (size_t)n * FIN + lane * 2) = lw;
}

// G2 = dinv[n]*(T[n] + sum T[j]) -> bf16 hi/lo   (256-dim; T pre-scaled by dinv)
__global__ __launch_bounds__(256) void k_aggH(const float* __restrict__ T,
                                              const int* __restrict__ csr_src,
                                              const int* __restrict__ row_start,
                                              const float* __restrict__ dinv,
                                              short* __restrict__ Ghi,
                                              short* __restrict__ Glo) {
    int wave = threadIdx.x >> 6, lane = threadIdx.x & 63;
    int n = blockIdx.x * 4 + wave;
    if (n >= NN) return;
    const float4* base = reinterpret_cast<const float4*>(T);
    float4 v = base[(size_t)n * 64 + lane];
    int s0 = row_start[n], s1 = row_start[n + 1];
    for (int j = s0; j < s1; ++j) {
        float4 u = base[(size_t)csr_src[j] * 64 + lane];
        v.x += u.x; v.y += u.y; v.z += u.z; v.w += u.w;
    }
    float g = dinv[n];
    float o[4] = {v.x * g, v.y * g, v.z * g, v.w * g};
    short4v h, lw;
#pragma unroll
    for (int j = 0; j < 4; ++j) {
        short hh = f2bf(o[j]);
        h[j] = hh;
        lw[j] = f2bf(o[j] - bf2f(hh));
    }
    *(short4v*)(Ghi + (size_t)n * HH + lane * 4) = h;
    *(short4v*)(Glo + (size_t)n * HH + lane * 4) = lw;
}

// ---------------- bf16-split MFMA stripe GEMM ----------------
// One block per 64-row stripe; A panel (hi+lo, full K) staged to LDS once;
// loops over NC in 64-col passes. B in [K/8][NC][8] hi/lo layout (L2-resident).
// EPI: 0 = +bias fp32 out. 1 = +bias relu bf16 hi/lo. 2 = bf16 out, split halves.

template<int K, int NC, int EPI>
__global__ __launch_bounds__(256, 2) void gemm_stripe(
    const short* __restrict__ Ahi, const short* __restrict__ Alo,
    const short* __restrict__ Bthi, const short* __restrict__ Btlo,
    const float* __restrict__ bias,
    float* __restrict__ OutF, short* __restrict__ OutH, short* __restrict__ OutL,
    short* __restrict__ OutA, short* __restrict__ OutB2, int M)
{
    constexpr int NKT = K / 32;
    constexpr int NSLAB = K / 8;
    constexpr int NPASS = NC / 64;
    __shared__ short lds[2 * NSLAB * 512];
    const int tid = threadIdx.x;
    const int w = tid >> 6, l = tid & 63;
    const int wr = w >> 1, wc = w & 1;
    const int m0 = blockIdx.x * 64;
    const int lhi = l >> 4, llo = l & 15;

    for (int s = w; s < 2 * NSLAB; s += 4) {
        int kg = (s < NSLAB) ? s : (s - NSLAB);
        const short* srcp = (s < NSLAB) ? Ahi : Alo;
        int row = m0 + l;
        if (row > M - 1) row = M - 1;
        short8v v = *(const short8v*)(srcp + (size_t)row * K + kg * 8);
        *(short8v*)(&lds[s * 512 + l * 8]) = v;
    }
    __syncthreads();

    for (int pass = 0; pass < NPASS; ++pass) {
        const int n0 = pass * 64 + wc * 32;
        f32x4 acc[2][2] = {};
#pragma unroll
        for (int kt = 0; kt < NKT; ++kt) {
            short8v bh[2], bl[2];
#pragma unroll
            for (int nt = 0; nt < 2; ++nt) {
                size_t idx = ((size_t)(kt * 4 + lhi) * NC + (n0 + nt * 16 + llo)) * 8;
                bh[nt] = *(const short8v*)(Bthi + idx);
                bl[nt] = *(const short8v*)(Btlo + idx);
            }
            short8v ah[2], al[2];
#pragma unroll
            for (int mt = 0; mt < 2; ++mt) {
                int off = (kt * 4 + lhi) * 512 + (wr * 32 + mt * 16 + llo) * 8;
                ah[mt] = *(const short8v*)(&lds[off]);
                al[mt] = *(const short8v*)(&lds[off + NSLAB * 512]);
            }
#pragma unroll
            for (int mt = 0; mt < 2; ++mt)
#pragma unroll
                for (int nt = 0; nt < 2; ++nt) {
                    acc[mt][nt] = __builtin_amdgcn_mfma_f32_16x16x32_bf16(ah[mt], bh[nt], acc[mt][nt], 0, 0, 0);
                    acc[mt][nt] = __builtin_amdgcn_mfma_f32_16x16x32_bf16(ah[mt], bl[nt], acc[mt][nt], 0, 0, 0);
                    acc[mt][nt] = __builtin_amdgcn_mfma_f32_16x16x32_bf16(al[mt], bh[nt], acc[mt][nt], 0, 0, 0);
                }
        }
#pragma unroll
        for (int mt = 0; mt < 2; ++mt)
#pragma unroll
            for (int r = 0; r < 4; ++r) {
                int gm = m0 + wr * 32 + mt * 16 + lhi * 4 + r;
                if (gm >= M) continue;
#pragma unroll
                for (int nt = 0; nt < 2; ++nt) {
                    int col = n0 + nt * 16 + llo;
                    float v = acc[mt][nt][r];
                    if constexpr (EPI == 0) {
                        OutF[(size_t)gm * NC + col] = v + bias[col];
                    } else if constexpr (EPI == 1) {
                        float o = fmaxf(v + bias[col], 0.0f);
                        short h = f2bf(o);
                        OutH[(size_t)gm * NC + col] = h;
                        OutL[(size_t)gm * NC + col] = f2bf(o - bf2f(h));
                    } else {
                        short h = f2bf(v);
                        if (col < NC / 2)
                            OutA[(size_t)gm * (NC / 2) + col] = h;
                        else
                            OutB2[(size_t)gm * (NC / 2) + col - NC / 2] = h;
                    }
                }
            }
    }
}

// ---------------- BatchNorm ----------------

__global__ __launch_bounds__(256) void k_bn_stats(const float* __restrict__ Hm,
                                                  float* __restrict__ ssum,
                                                  float* __restrict__ ssq) {
    int c = threadIdx.x;
    int r0 = blockIdx.x * 64;
    int r1 = min(r0 + 64, NN);
    float s = 0.f, q = 0.f;
    for (int r = r0; r < r1; ++r) {
        float v = Hm[(size_t)r * HH + c];
        s += v;
        q += v * v;
    }
    atomicAdd(&ssum[c], s);
    atomicAdd(&ssq[c], q);
}

__global__ void k_bn_final(const float* __restrict__ ssum, const float* __restrict__ ssq,
                           const float* __restrict__ gamma, const float* __restrict__ beta,
                           float* __restrict__ scale, float* __restrict__ shift) {
    int c = threadIdx.x;
    float mu = ssum[c] / (float)NN;
    float var = ssq[c] / (float)NN - mu * mu;
    float rstd = rsqrtf(var + BN_EPS);
    float sc = rstd * gamma[c];
    scale[c] = sc;
    shift[c] = beta[c] - mu * sc;
}

// T = dinv_row * relu(scale*P1 + shift)   (fp32, feeds layer-2 aggregation)
__global__ void k_bn_apply_T(const float* __restrict__ P1, const float* __restrict__ scale,
                             const float* __restrict__ shift, const float* __restrict__ dinv,
                             float* __restrict__ T) {
    int i4 = blockIdx.x * 256 + threadIdx.x;
    if (i4 >= NN * HH / 4) return;
    int c4 = i4 & 63;
    float g = dinv[i4 >> 6];
    float4 v = reinterpret_cast<const float4*>(P1)[i4];
    float4 sc = reinterpret_cast<const float4*>(scale)[c4];
    float4 sh = reinterpret_cast<const float4*>(shift)[c4];
    v.x = g * fmaxf(v.x * sc.x + sh.x, 0.f);
    v.y = g * fmaxf(v.y * sc.y + sh.y, 0.f);
    v.z = g * fmaxf(v.z * sc.z + sh.z, 0.f);
    v.w = g * fmaxf(v.w * sc.w + sh.w, 0.f);
    reinterpret_cast<float4*>(T)[i4] = v;
}

// ---------------- edge head: sigmoid(relu(A[src]+B[dst]+bm1) . Wm2 + bm2) ----------------

__global__ __launch_bounds__(256) void k_edge(const short* __restrict__ Aarr,
                                              const short* __restrict__ Barr,
                                              const int* __restrict__ src,
                                              const int* __restrict__ dst,
                                              const float* __restrict__ bm1,
                                              const float* __restrict__ Wm2,
                                              const float* __restrict__ bm2,
                                              float* __restrict__ out) {
    int wave = threadIdx.x >> 6;
    int lane = threadIdx.x & 63;
    int e = blockIdx.x * 4 + wave;
    if (e >= EE) return;
    int s = src[e], d = dst[e];
    short4v a = *(const short4v*)(Aarr + (size_t)s * 256 + lane * 4);
    short4v b = *(const short4v*)(Barr + (size_t)d * 256 + lane * 4);
    float4 bb = reinterpret_cast<const float4*>(bm1)[lane];
    float4 w = reinterpret_cast<const float4*>(Wm2)[lane];
    float t = fmaxf(bf2f(a[0]) + bf2f(b[0]) + bb.x, 0.f) * w.x
            + fmaxf(bf2f(a[1]) + bf2f(b[1]) + bb.y, 0.f) * w.y
            + fmaxf(bf2f(a[2]) + bf2f(b[2]) + bb.z, 0.f) * w.z
            + fmaxf(bf2f(a[3]) + bf2f(b[3]) + bb.w, 0.f) * w.w;
#pragma unroll
    for (int off = 32; off; off >>= 1) t += __shfl_xor(t, off);
    if (lane == 0) {
        float z = t + bm2[0];
        out[e] = 1.0f / (1.0f + expf(-z));
    }
}

// ---------------- launch ----------------

extern "C" void kernel_launch(void* const* d_in, const int* in_sizes, int n_in,
                              void* d_out, int out_size, void* d_ws, size_t ws_size,
                              hipStream_t stream) {
    const float* x     = (const float*)d_in[0];
    const int*   ei    = (const int*)d_in[1];
    const float* W1    = (const float*)d_in[2];
    const float* b1    = (const float*)d_in[3];
    const float* gamma = (const float*)d_in[4];
    const float* beta  = (const float*)d_in[5];
    const float* W2    = (const float*)d_in[6];
    const float* b2    = (const float*)d_in[7];
    const float* Wm1   = (const float*)d_in[8];
    const float* bm1   = (const float*)d_in[9];
    const float* Wm2   = (const float*)d_in[10];
    const float* bm2   = (const float*)d_in[11];
    float* out = (float*)d_out;
    const int* src = ei;
    const int* dst = ei + EE;

    char* ws = (char*)d_ws;
    size_t off = 0;
    auto take = [&](size_t b) -> char* {
        char* p = ws + off;
        off += (b + 255) & ~(size_t)255;
        return p;
    };
    // small tables (~3.3 MB)
    int*   deg_cnt   = (int*)take((size_t)NN * 4);
    float* dinv      = (float*)take((size_t)NN * 4);
    int*   row_start = (int*)take((size_t)(NN + 1) * 4);
    int*   cursor    = (int*)take((size_t)NN * 4);
    int*   csr_src   = (int*)take((size_t)EE * 4);
    int*   bsum      = (int*)take((size_t)NSB * 4);
    int*   boff      = (int*)take((size_t)NSB * 4);
    float* ssum      = (float*)take(1024);
    float* ssq       = (float*)take(1024);
    float* scale     = (float*)take(1024);
    float* shift     = (float*)take(1024);
    short* W1thi     = (short*)take((size_t)128 * 256 * 2);
    short* W1tlo     = (short*)take((size_t)128 * 256 * 2);
    short* W2thi     = (short*)take((size_t)256 * 256 * 2);
    short* W2tlo     = (short*)take((size_t)256 * 256 * 2);
    short* Wcthi     = (short*)take((size_t)256 * 512 * 2);
    short* Wctlo     = (short*)take((size_t)256 * 512 * 2);
    // three 51.2 MB slots, liveness-aliased (peak ~157 MB, known to fit)
    const size_t SLOT = (size_t)NN * HH * 4;  // 51,200,000
    char* slotA = take(SLOT);
    char* slotB = take(SLOT);
    char* slotC = take(SLOT);

    short* G1hi = (short*)slotB;                    // [N,128] bf16 12.8 MB
    short* G1lo = (short*)(slotB + 12800000);
    float* P1   = (float*)slotC;                    // [N,256] fp32
    float* T    = (float*)slotA;                    // [N,256] fp32
    short* G2hi = (short*)slotB;                    // [N,256] bf16 (G1 dead)
    short* G2lo = (short*)(slotB + 25600000);
    short* H2hi = (short*)slotC;                    // [N,256] bf16 (P1 dead)
    short* H2lo = (short*)(slotC + 25600000);
    short* Aarr = (short*)slotA;                    // [N,256] bf16 (T dead)
    short* Barr = (short*)(slotA + 25600000);
    (void)ssq; (void)ws_size;

    hipMemsetAsync(deg_cnt, 0, (size_t)NN * 4, stream);
    hipMemsetAsync(ssum, 0, 2048, stream);  // ssum + ssq adjacent

    k_count<<<(EE + 255) / 256, 256, 0, stream>>>(dst, deg_cnt);
    k_scan1<<<NSB, 256, 0, stream>>>(deg_cnt, bsum);
    k_scan2<<<1, 256, 0, stream>>>(bsum, boff, row_start);
    k_scan3<<<NSB, 256, 0, stream>>>(deg_cnt, boff, row_start, cursor, dinv);
    k_fill<<<(EE + 255) / 256, 256, 0, stream>>>(src, dst, cursor, csr_src);
    k_wsplit<<<(128 * 256 + 255) / 256, 256, 0, stream>>>(W1, W1thi, W1tlo, 128, 256);
    k_wsplit<<<(256 * 256 + 255) / 256, 256, 0, stream>>>(W2, W2thi, W2tlo, 256, 256);
    k_wsplit_cat<<<(256 * 512 + 255) / 256, 256, 0, stream>>>(Wm1, Wcthi, Wctlo);

    const int MB = (NN + 63) / 64;  // 782
    // layer 1 (aggregate-first, scale fused): G1 = dinv*(dinv*x + gather(dinv*x)) ; P1 = G1@W1 + b1
    k_aggX<<<(NN + 3) / 4, 256, 0, stream>>>(x, csr_src, row_start, dinv, G1hi, G1lo);
    gemm_stripe<128, 256, 0><<<MB, 256, 0, stream>>>(G1hi, G1lo, W1thi, W1tlo, b1,
                                                     P1, nullptr, nullptr, nullptr, nullptr, NN);
    // batchnorm; T = dinv * relu(BN(P1))
    k_bn_stats<<<(NN + 63) / 64, 256, 0, stream>>>(P1, ssum, ssq);
    k_bn_final<<<1, 256, 0, stream>>>(ssum, ssq, gamma, beta, scale, shift);
    k_bn_apply_T<<<NN * HH / 4 / 256, 256, 0, stream>>>(P1, scale, shift, dinv, T);
    // layer 2: G2 = dinv*(T + gather) ; H2 = relu(G2@W2 + b2) (bf16 hi/lo, fused)
    k_aggH<<<(NN + 3) / 4, 256, 0, stream>>>(T, csr_src, row_start, dinv, G2hi, G2lo);
    gemm_stripe<256, 256, 1><<<MB, 256, 0, stream>>>(G2hi, G2lo, W2thi, W2tlo, b2,
                                                     nullptr, H2hi, H2lo, nullptr, nullptr, NN);
    // edge-head node factors: [Aarr | Barr] = H2 @ Wcat (bf16 out)
    gemm_stripe<256, 512, 2><<<MB, 256, 0, stream>>>(H2hi, H2lo, Wcthi, Wctlo, nullptr,
                                                     nullptr, nullptr, nullptr, Aarr, Barr, NN);
    // edge head
    k_edge<<<(EE + 3) / 4, 256, 0, stream>>>(Aarr, Barr, src, dst, bm1, Wm2, bm2, out);
}